// Round 4
// baseline (447.982 us; speedup 1.0000x reference)
//
#include <hip/hip_runtime.h>
#include <hip/hip_bf16.h>
#include <math.h>

// ---------------------------------------------------------------------------
// SAINT-style 2-layer graph conv + linear head + log_softmax
// N=100000 nodes, E=1600000 edges, C=64, HID=64, OUT=40  (all f32)
// Round 3: k_final -> lane=node (SGPR weights, no broadcast-LDS bottleneck);
//          k_spmm  -> float4 gathers, 4 edges/step (4x fewer TCC requests).
// ---------------------------------------------------------------------------

#define BROWS 512
#define BIN_CHUNK 8192

// ---- pass A: bin edges into NB bucket regions, packed (lrow<<17)|col -------
__global__ __launch_bounds__(256) void k_binA(
    const int* __restrict__ row, const int* __restrict__ col,
    unsigned* __restrict__ bCnt, unsigned* __restrict__ pairs,
    int nE, int NB, int capA)
{
  __shared__ unsigned cnt[256], base[256], gb[256], sc[256];
  __shared__ unsigned buf[BIN_CHUNK];
  const int t = threadIdx.x;
  const int tb = blockIdx.x * BIN_CHUNK;

  cnt[t] = 0;
  __syncthreads();

  unsigned pk[32];
  unsigned short po[32];
  short bk[32];
#pragma unroll
  for (int j = 0; j < 32; ++j) {
    int i = tb + j * 256 + t;
    if (i < nE) {
      int r = row[i], c = col[i];
      int b = r >> 9;
      pk[j] = ((unsigned)(r & (BROWS - 1)) << 17) | (unsigned)c;
      bk[j] = (short)b;
      po[j] = (unsigned short)atomicAdd(&cnt[b], 1u);
    } else bk[j] = -1;
  }
  __syncthreads();
  sc[t] = cnt[t];
  __syncthreads();
  for (int off = 1; off < 256; off <<= 1) {
    unsigned v = (t >= off) ? sc[t - off] : 0u;
    __syncthreads();
    sc[t] += v;
    __syncthreads();
  }
  base[t] = t ? sc[t - 1] : 0u;
  __syncthreads();
#pragma unroll
  for (int j = 0; j < 32; ++j)
    if (bk[j] >= 0) buf[base[bk[j]] + po[j]] = pk[j];
  unsigned c = cnt[t];
  gb[t] = c ? atomicAdd(&bCnt[t], c) : 0u;
  __syncthreads();
  for (int b = 0; b < NB; ++b) {
    unsigned cb = cnt[b];
    if (!cb) continue;
    unsigned lo = base[b], g = gb[b];
    size_t dst = (size_t)b * (unsigned)capA;
    for (unsigned u = t; u < cb; u += 256)
      if (g + u < (unsigned)capA) pairs[dst + g + u] = buf[lo + u];
  }
}

__global__ __launch_bounds__(256) void k_bscan(const unsigned* __restrict__ bCnt,
                                               unsigned* __restrict__ bBase,
                                               int NB, int capA) {
  __shared__ unsigned sc[256];
  int t = threadIdx.x;
  unsigned v = (t < NB) ? min(bCnt[t], (unsigned)capA) : 0u;
  sc[t] = v;
  __syncthreads();
  for (int off = 1; off < 256; off <<= 1) {
    unsigned u = (t >= off) ? sc[t - off] : 0u;
    __syncthreads();
    sc[t] += u;
    __syncthreads();
  }
  if (t < NB) bBase[t] = t ? sc[t - 1] : 0u;
}

__global__ __launch_bounds__(256) void k_binB(
    const unsigned* __restrict__ pairs, const unsigned* __restrict__ bCnt,
    const unsigned* __restrict__ bBase, int* __restrict__ colS,
    unsigned* __restrict__ start, float* __restrict__ dis,
    int N, int capA)
{
  __shared__ unsigned hist[BROWS], ex[BROWS], cur[BROWS], sc[256];
  __shared__ unsigned cols[12288];
  const int t = threadIdx.x;
  const int b = blockIdx.x;
  const unsigned cnt = min(bCnt[b], (unsigned)capA);
  const unsigned gbase = bBase[b];
  const size_t src = (size_t)b * (unsigned)capA;

  hist[t] = 0; hist[256 + t] = 0;
  __syncthreads();
  for (unsigned i = t; i < cnt; i += 256)
    atomicAdd(&hist[pairs[src + i] >> 17], 1u);
  __syncthreads();
  unsigned h0 = hist[2 * t], h1 = hist[2 * t + 1];
  sc[t] = h0 + h1;
  __syncthreads();
  for (int off = 1; off < 256; off <<= 1) {
    unsigned v = (t >= off) ? sc[t - off] : 0u;
    __syncthreads();
    sc[t] += v;
    __syncthreads();
  }
  unsigned bexc = t ? sc[t - 1] : 0u;
  ex[2 * t] = bexc;          cur[2 * t] = bexc;
  ex[2 * t + 1] = bexc + h0; cur[2 * t + 1] = bexc + h0;
  __syncthreads();
  for (unsigned i = t; i < cnt; i += 256) {
    unsigned p = pairs[src + i];
    unsigned pos = atomicAdd(&cur[p >> 17], 1u);
    cols[pos] = p & 0x1FFFFu;
  }
  __syncthreads();
  for (unsigned i = t; i < cnt; i += 256)
    colS[gbase + i] = (int)cols[i];
  const int rowBase = b * BROWS;
#pragma unroll
  for (int j = 0; j < BROWS / 256; ++j) {
    int lr = j * 256 + t;
    int n = rowBase + lr;
    if (n < N) {
      unsigned d = hist[lr];
      start[n] = gbase + ex[lr] + d;
      dis[n] = d ? rsqrtf((float)d) : 0.f;
    }
  }
}

// ---------------- fallback-path kernels (round-1 CSR build) -----------------
__global__ __launch_bounds__(256) void k_deg(const int* __restrict__ row,
                                             unsigned* __restrict__ deg, int nE) {
  int i = blockIdx.x * blockDim.x + threadIdx.x;
  int stride = gridDim.x * blockDim.x;
  for (; i < nE; i += stride) atomicAdd(&deg[row[i]], 1u);
}

__global__ __launch_bounds__(256) void k_dis(const unsigned* __restrict__ deg,
                                             float* __restrict__ dis, int n) {
  int i = blockIdx.x * blockDim.x + threadIdx.x;
  if (i < n) {
    unsigned d = deg[i];
    dis[i] = d > 0u ? rsqrtf((float)d) : 0.f;
  }
}

__global__ __launch_bounds__(256) void k_scan1(const unsigned* __restrict__ deg,
                                               unsigned* __restrict__ start,
                                               unsigned* __restrict__ bsum, int n) {
  __shared__ unsigned s[256];
  const int base = blockIdx.x * 2048;
  unsigned v[8], tsum = 0;
#pragma unroll
  for (int j = 0; j < 8; ++j) {
    int idx = base + threadIdx.x * 8 + j;
    v[j] = idx < n ? deg[idx] : 0u;
    tsum += v[j];
  }
  s[threadIdx.x] = tsum;
  __syncthreads();
  for (int off = 1; off < 256; off <<= 1) {
    unsigned t = (threadIdx.x >= off) ? s[threadIdx.x - off] : 0u;
    __syncthreads();
    s[threadIdx.x] += t;
    __syncthreads();
  }
  unsigned run = threadIdx.x ? s[threadIdx.x - 1] : 0u;
  if (threadIdx.x == 255) bsum[blockIdx.x] = s[255];
#pragma unroll
  for (int j = 0; j < 8; ++j) {
    int idx = base + threadIdx.x * 8 + j;
    if (idx < n) start[idx] = run;
    run += v[j];
  }
}

__global__ void k_scan2(unsigned* __restrict__ bsum, int nB) {
  if (threadIdx.x == 0 && blockIdx.x == 0) {
    unsigned run = 0;
    for (int b = 0; b < nB; ++b) { unsigned t = bsum[b]; bsum[b] = run; run += t; }
  }
}

__global__ __launch_bounds__(256) void k_scan3(unsigned* __restrict__ start,
                                               const unsigned* __restrict__ bsum, int n) {
  int i = blockIdx.x * blockDim.x + threadIdx.x;
  if (i < n) start[i] += bsum[i >> 11];
}

__global__ __launch_bounds__(256) void k_build(const int* __restrict__ row,
                                               const int* __restrict__ col,
                                               unsigned* __restrict__ start,
                                               int* __restrict__ colS, int nE) {
  int i = blockIdx.x * blockDim.x + threadIdx.x;
  int stride = gridDim.x * blockDim.x;
  for (; i < nE; i += stride) {
    int r = row[i];
    unsigned p = atomicAdd(&start[r], 1u);
    colS[p] = col[i];
  }
}

// ---------------- shared compute kernels ------------------------------------
__global__ __launch_bounds__(256) void k_gemm_dual(
    const float* __restrict__ x, const float* __restrict__ W,
    const float* __restrict__ b, const float* __restrict__ Wr,
    const float* __restrict__ br, float* __restrict__ h,
    float* __restrict__ agg, int nNodes, int reluIn)
{
  __shared__ float4 xrow4[4][16];
  const int t = threadIdx.x, wave = t >> 6, lane = t & 63;
  const float4* W4  = (const float4*)W;
  const float4* Wr4 = (const float4*)Wr;
  float4 w4[16], wr4[16];
#pragma unroll
  for (int i = 0; i < 16; ++i) { w4[i] = W4[lane * 16 + i]; wr4[i] = Wr4[lane * 16 + i]; }
  const float bo = b[lane], bro = br[lane];
  float* xs = (float*)&xrow4[wave][0];
  const int gw = blockIdx.x * 4 + wave, nW = gridDim.x * 4;
  for (int n = gw; n < nNodes; n += nW) {
    float xv = x[(size_t)n * 64 + lane];
    if (reluIn) xv = fmaxf(xv, 0.f);
    xs[lane] = xv;
    float ha = bo, aa = bro;
#pragma unroll
    for (int k4 = 0; k4 < 16; ++k4) {
      float4 xk = xrow4[wave][k4];
      ha += xk.x * w4[k4].x + xk.y * w4[k4].y + xk.z * w4[k4].z + xk.w * w4[k4].w;
      aa += xk.x * wr4[k4].x + xk.y * wr4[k4].y + xk.z * wr4[k4].z + xk.w * wr4[k4].w;
    }
    h[(size_t)n * 64 + lane]   = ha;
    agg[(size_t)n * 64 + lane] = aa;
  }
}

// agg[n,:] += dis[n] * sum_{e in seg(n)} dis[colS[e]] * h[colS[e],:]
// one wave per node; 4 edge-groups x 16 lanes; float4 gathers.
__global__ __launch_bounds__(256) void k_spmm(
    const float* __restrict__ h, float* __restrict__ agg,
    const int* __restrict__ colS, const unsigned* __restrict__ startEnd,
    const float* __restrict__ dis, int nNodes)
{
  const int t = threadIdx.x, wave = t >> 6, lane = t & 63;
  const int g = lane >> 4, sub = lane & 15;
  const int n = blockIdx.x * 4 + wave;
  if (n >= nNodes) return;
  const unsigned lo = n ? startEnd[n - 1] : 0u;
  const unsigned hi = startEnd[n];
  const float4* h4 = (const float4*)h;
  float ax = 0.f, ay = 0.f, az = 0.f, aw = 0.f;
  for (unsigned base = lo; base < hi; base += 64) {
    const int cnt = (int)min(64u, hi - base);
    int   myc = (lane < cnt) ? colS[base + lane] : 0;
    float myw = (lane < cnt) ? dis[myc] : 0.f;
    for (int j = 0; j < cnt; j += 4) {
      int jj = j + g;                         // lanes with jj>=cnt hold c=0,w=0
      int   c = __shfl(myc, jj);
      float w = __shfl(myw, jj);
      float4 v = h4[(size_t)c * 16 + sub];
      ax += w * v.x; ay += w * v.y; az += w * v.z; aw += w * v.w;
    }
  }
  // butterfly-reduce the 4 groups (lane bits 4,5)
  ax += __shfl_xor(ax, 16); ay += __shfl_xor(ay, 16);
  az += __shfl_xor(az, 16); aw += __shfl_xor(aw, 16);
  ax += __shfl_xor(ax, 32); ay += __shfl_xor(ay, 32);
  az += __shfl_xor(az, 32); aw += __shfl_xor(aw, 32);
  if (lane < 16) {
    const float dn = dis[n];
    float4* a4 = (float4*)(agg + (size_t)n * 64);
    float4 o = a4[sub];
    o.x += dn * ax; o.y += dn * ay; o.z += dn * az; o.w += dn * aw;
    a4[sub] = o;
  }
}

// out[n,:] = log_softmax( concat(relu(agg1[n]), relu(agg2[n])) @ Wl^T + bl )
// lane = node; x in VGPRs, Wl rows via scalar loads (wave-uniform).
__global__ __launch_bounds__(256) void k_final(
    const float* __restrict__ agg1, const float* __restrict__ agg2,
    const float* __restrict__ Wl, const float* __restrict__ bl,
    float* __restrict__ out, int nNodes)
{
  __shared__ float slog[40 * 256];   // [o][tid] — per-lane column, no sync
  const int t = threadIdx.x;
  const int n = blockIdx.x * 256 + t;
  if (n >= nNodes) return;

  float4 x[32];
  {
    const float4* a1 = (const float4*)(agg1 + (size_t)n * 64);
    const float4* a2 = (const float4*)(agg2 + (size_t)n * 64);
#pragma unroll
    for (int i = 0; i < 16; ++i) {
      float4 v = a1[i];
      x[i] = make_float4(fmaxf(v.x, 0.f), fmaxf(v.y, 0.f), fmaxf(v.z, 0.f), fmaxf(v.w, 0.f));
    }
#pragma unroll
    for (int i = 0; i < 16; ++i) {
      float4 v = a2[i];
      x[16 + i] = make_float4(fmaxf(v.x, 0.f), fmaxf(v.y, 0.f), fmaxf(v.z, 0.f), fmaxf(v.w, 0.f));
    }
  }

  const float4* W4 = (const float4*)Wl;    // row o = W4[o*32 + k], uniform
  for (int o = 0; o < 40; ++o) {
    float acc = bl[o];
#pragma unroll
    for (int k = 0; k < 32; ++k) {
      float4 w = W4[o * 32 + k];
      acc += w.x * x[k].x + w.y * x[k].y + w.z * x[k].z + w.w * x[k].w;
    }
    slog[o * 256 + t] = acc;
  }

  float l[40];
#pragma unroll
  for (int o = 0; o < 40; ++o) l[o] = slog[o * 256 + t];
  float m = l[0];
#pragma unroll
  for (int o = 1; o < 40; ++o) m = fmaxf(m, l[o]);
  float s = 0.f;
#pragma unroll
  for (int o = 0; o < 40; ++o) s += __expf(l[o] - m);
  const float lse = m + __logf(s);
  float4* o4 = (float4*)(out + (size_t)n * 40);
#pragma unroll
  for (int q = 0; q < 10; ++q) {
    float4 r = make_float4(l[4 * q] - lse, l[4 * q + 1] - lse,
                           l[4 * q + 2] - lse, l[4 * q + 3] - lse);
    o4[q] = r;
  }
}

extern "C" void kernel_launch(void* const* d_in, const int* in_sizes, int n_in,
                              void* d_out, int out_size, void* d_ws, size_t ws_size,
                              hipStream_t stream) {
  const float* x0  = (const float*)d_in[0];
  const int*   ei  = (const int*)d_in[1];
  const float* W1  = (const float*)d_in[2];
  const float* b1  = (const float*)d_in[3];
  const float* Wr1 = (const float*)d_in[4];
  const float* br1 = (const float*)d_in[5];
  const float* W2  = (const float*)d_in[6];
  const float* b2  = (const float*)d_in[7];
  const float* Wr2 = (const float*)d_in[8];
  const float* br2 = (const float*)d_in[9];
  const float* Wl  = (const float*)d_in[10];
  const float* bl  = (const float*)d_in[11];
  float* out = (float*)d_out;

  const int N = in_sizes[0] / 64;
  const int E = in_sizes[1] / 2;
  const int* row = ei;
  const int* col = ei + E;

  const int NB = (N + BROWS - 1) / BROWS;
  const int capA = 12288;
  const int avg = E / (NB > 0 ? NB : 1);
  const bool binOK = (N <= 131072) && (NB <= 256) &&
                     (avg + 12 * (int)sqrtf((float)avg + 1.f) + 256 <= capA);

  const size_t needBin = (size_t)4 * (512 + (size_t)NB * capA + (size_t)E + (size_t)2 * N + (size_t)192 * N);
  const size_t needCSR = (size_t)4 * ((size_t)3 * N + 64 + (size_t)E + (size_t)192 * N);

  if (binOK && ws_size >= needBin) {
    unsigned* bCnt  = (unsigned*)d_ws;
    unsigned* bBase = bCnt + 256;
    unsigned* pairs = bBase + 256;
    int*      colS  = (int*)(pairs + (size_t)NB * capA);
    unsigned* start = (unsigned*)(colS + E);
    float*    dis   = (float*)(start + N);
    float*    h     = dis + N;
    float*    agg1  = h + (size_t)64 * N;
    float*    agg2  = agg1 + (size_t)64 * N;

    hipMemsetAsync(bCnt, 0, 256 * 4, stream);
    k_binA<<<(E + BIN_CHUNK - 1) / BIN_CHUNK, 256, 0, stream>>>(row, col, bCnt, pairs, E, NB, capA);
    k_bscan<<<1, 256, 0, stream>>>(bCnt, bBase, NB, capA);
    k_binB<<<NB, 256, 0, stream>>>(pairs, bCnt, bBase, colS, start, dis, N, capA);

    k_gemm_dual<<<2048, 256, 0, stream>>>(x0, W1, b1, Wr1, br1, h, agg1, N, 0);
    k_spmm<<<(N + 3) / 4, 256, 0, stream>>>(h, agg1, colS, start, dis, N);

    k_gemm_dual<<<2048, 256, 0, stream>>>(agg1, W2, b2, Wr2, br2, h, agg2, N, 1);
    k_spmm<<<(N + 3) / 4, 256, 0, stream>>>(h, agg2, colS, start, dis, N);

    k_final<<<(N + 255) / 256, 256, 0, stream>>>(agg1, agg2, Wl, bl, out, N);
  } else if (ws_size >= needCSR) {
    unsigned* deg   = (unsigned*)d_ws;
    unsigned* start = deg + N;
    float*    dis   = (float*)(start + N);
    unsigned* bsum  = (unsigned*)(dis + N);
    int*      colS  = (int*)(bsum + 64);
    float*    h     = (float*)(colS + E);
    float*    agg1  = h + (size_t)64 * N;
    float*    agg2  = agg1 + (size_t)64 * N;

    const int nB = (N + 2047) / 2048;

    hipMemsetAsync(deg, 0, (size_t)N * 4, stream);
    k_deg<<<1024, 256, 0, stream>>>(row, deg, E);
    k_dis<<<(N + 255) / 256, 256, 0, stream>>>(deg, dis, N);
    k_scan1<<<nB, 256, 0, stream>>>(deg, start, bsum, N);
    k_scan2<<<1, 64, 0, stream>>>(bsum, nB);
    k_scan3<<<(N + 255) / 256, 256, 0, stream>>>(start, bsum, N);
    k_build<<<1024, 256, 0, stream>>>(row, col, start, colS, E);

    k_gemm_dual<<<2048, 256, 0, stream>>>(x0, W1, b1, Wr1, br1, h, agg1, N, 0);
    k_spmm<<<(N + 3) / 4, 256, 0, stream>>>(h, agg1, colS, start, dis, N);

    k_gemm_dual<<<2048, 256, 0, stream>>>(agg1, W2, b2, Wr2, br2, h, agg2, N, 1);
    k_spmm<<<(N + 3) / 4, 256, 0, stream>>>(h, agg2, colS, start, dis, N);

    k_final<<<(N + 255) / 256, 256, 0, stream>>>(agg1, agg2, Wl, bl, out, N);
  }
}

// Round 5
// 369.196 us; speedup vs baseline: 1.2134x; 1.2134x over previous
//
#include <hip/hip_runtime.h>
#include <hip/hip_bf16.h>
#include <math.h>

// ---------------------------------------------------------------------------
// SAINT-style 2-layer graph conv + linear head + log_softmax
// N=100000 nodes, E=1600000 edges, C=64, HID=64, OUT=40  (all f32)
// Round 4: k_final -> 64 nodes/block, lane=node, wave=output-group (scalar Wl),
//          LDS x-tile (pad 33), cross-wave softmax via tiny LDS. k_spmm: 2-deep
//          gather unroll.
// ---------------------------------------------------------------------------

#define BROWS 512
#define BIN_CHUNK 8192

// ---- pass A: bin edges into NB bucket regions, packed (lrow<<17)|col -------
__global__ __launch_bounds__(256) void k_binA(
    const int* __restrict__ row, const int* __restrict__ col,
    unsigned* __restrict__ bCnt, unsigned* __restrict__ pairs,
    int nE, int NB, int capA)
{
  __shared__ unsigned cnt[256], base[256], gb[256], sc[256];
  __shared__ unsigned buf[BIN_CHUNK];
  const int t = threadIdx.x;
  const int tb = blockIdx.x * BIN_CHUNK;

  cnt[t] = 0;
  __syncthreads();

  unsigned pk[32];
  unsigned short po[32];
  short bk[32];
#pragma unroll
  for (int j = 0; j < 32; ++j) {
    int i = tb + j * 256 + t;
    if (i < nE) {
      int r = row[i], c = col[i];
      int b = r >> 9;
      pk[j] = ((unsigned)(r & (BROWS - 1)) << 17) | (unsigned)c;
      bk[j] = (short)b;
      po[j] = (unsigned short)atomicAdd(&cnt[b], 1u);
    } else bk[j] = -1;
  }
  __syncthreads();
  sc[t] = cnt[t];
  __syncthreads();
  for (int off = 1; off < 256; off <<= 1) {
    unsigned v = (t >= off) ? sc[t - off] : 0u;
    __syncthreads();
    sc[t] += v;
    __syncthreads();
  }
  base[t] = t ? sc[t - 1] : 0u;
  __syncthreads();
#pragma unroll
  for (int j = 0; j < 32; ++j)
    if (bk[j] >= 0) buf[base[bk[j]] + po[j]] = pk[j];
  unsigned c = cnt[t];
  gb[t] = c ? atomicAdd(&bCnt[t], c) : 0u;
  __syncthreads();
  for (int b = 0; b < NB; ++b) {
    unsigned cb = cnt[b];
    if (!cb) continue;
    unsigned lo = base[b], g = gb[b];
    size_t dst = (size_t)b * (unsigned)capA;
    for (unsigned u = t; u < cb; u += 256)
      if (g + u < (unsigned)capA) pairs[dst + g + u] = buf[lo + u];
  }
}

__global__ __launch_bounds__(256) void k_bscan(const unsigned* __restrict__ bCnt,
                                               unsigned* __restrict__ bBase,
                                               int NB, int capA) {
  __shared__ unsigned sc[256];
  int t = threadIdx.x;
  unsigned v = (t < NB) ? min(bCnt[t], (unsigned)capA) : 0u;
  sc[t] = v;
  __syncthreads();
  for (int off = 1; off < 256; off <<= 1) {
    unsigned u = (t >= off) ? sc[t - off] : 0u;
    __syncthreads();
    sc[t] += u;
    __syncthreads();
  }
  if (t < NB) bBase[t] = t ? sc[t - 1] : 0u;
}

__global__ __launch_bounds__(256) void k_binB(
    const unsigned* __restrict__ pairs, const unsigned* __restrict__ bCnt,
    const unsigned* __restrict__ bBase, int* __restrict__ colS,
    unsigned* __restrict__ start, float* __restrict__ dis,
    int N, int capA)
{
  __shared__ unsigned hist[BROWS], ex[BROWS], cur[BROWS], sc[256];
  __shared__ unsigned cols[12288];
  const int t = threadIdx.x;
  const int b = blockIdx.x;
  const unsigned cnt = min(bCnt[b], (unsigned)capA);
  const unsigned gbase = bBase[b];
  const size_t src = (size_t)b * (unsigned)capA;

  hist[t] = 0; hist[256 + t] = 0;
  __syncthreads();
  for (unsigned i = t; i < cnt; i += 256)
    atomicAdd(&hist[pairs[src + i] >> 17], 1u);
  __syncthreads();
  unsigned h0 = hist[2 * t], h1 = hist[2 * t + 1];
  sc[t] = h0 + h1;
  __syncthreads();
  for (int off = 1; off < 256; off <<= 1) {
    unsigned v = (t >= off) ? sc[t - off] : 0u;
    __syncthreads();
    sc[t] += v;
    __syncthreads();
  }
  unsigned bexc = t ? sc[t - 1] : 0u;
  ex[2 * t] = bexc;          cur[2 * t] = bexc;
  ex[2 * t + 1] = bexc + h0; cur[2 * t + 1] = bexc + h0;
  __syncthreads();
  for (unsigned i = t; i < cnt; i += 256) {
    unsigned p = pairs[src + i];
    unsigned pos = atomicAdd(&cur[p >> 17], 1u);
    cols[pos] = p & 0x1FFFFu;
  }
  __syncthreads();
  for (unsigned i = t; i < cnt; i += 256)
    colS[gbase + i] = (int)cols[i];
  const int rowBase = b * BROWS;
#pragma unroll
  for (int j = 0; j < BROWS / 256; ++j) {
    int lr = j * 256 + t;
    int n = rowBase + lr;
    if (n < N) {
      unsigned d = hist[lr];
      start[n] = gbase + ex[lr] + d;
      dis[n] = d ? rsqrtf((float)d) : 0.f;
    }
  }
}

// ---------------- fallback-path kernels (round-1 CSR build) -----------------
__global__ __launch_bounds__(256) void k_deg(const int* __restrict__ row,
                                             unsigned* __restrict__ deg, int nE) {
  int i = blockIdx.x * blockDim.x + threadIdx.x;
  int stride = gridDim.x * blockDim.x;
  for (; i < nE; i += stride) atomicAdd(&deg[row[i]], 1u);
}

__global__ __launch_bounds__(256) void k_dis(const unsigned* __restrict__ deg,
                                             float* __restrict__ dis, int n) {
  int i = blockIdx.x * blockDim.x + threadIdx.x;
  if (i < n) {
    unsigned d = deg[i];
    dis[i] = d > 0u ? rsqrtf((float)d) : 0.f;
  }
}

__global__ __launch_bounds__(256) void k_scan1(const unsigned* __restrict__ deg,
                                               unsigned* __restrict__ start,
                                               unsigned* __restrict__ bsum, int n) {
  __shared__ unsigned s[256];
  const int base = blockIdx.x * 2048;
  unsigned v[8], tsum = 0;
#pragma unroll
  for (int j = 0; j < 8; ++j) {
    int idx = base + threadIdx.x * 8 + j;
    v[j] = idx < n ? deg[idx] : 0u;
    tsum += v[j];
  }
  s[threadIdx.x] = tsum;
  __syncthreads();
  for (int off = 1; off < 256; off <<= 1) {
    unsigned t = (threadIdx.x >= off) ? s[threadIdx.x - off] : 0u;
    __syncthreads();
    s[threadIdx.x] += t;
    __syncthreads();
  }
  unsigned run = threadIdx.x ? s[threadIdx.x - 1] : 0u;
  if (threadIdx.x == 255) bsum[blockIdx.x] = s[255];
#pragma unroll
  for (int j = 0; j < 8; ++j) {
    int idx = base + threadIdx.x * 8 + j;
    if (idx < n) start[idx] = run;
    run += v[j];
  }
}

__global__ void k_scan2(unsigned* __restrict__ bsum, int nB) {
  if (threadIdx.x == 0 && blockIdx.x == 0) {
    unsigned run = 0;
    for (int b = 0; b < nB; ++b) { unsigned t = bsum[b]; bsum[b] = run; run += t; }
  }
}

__global__ __launch_bounds__(256) void k_scan3(unsigned* __restrict__ start,
                                               const unsigned* __restrict__ bsum, int n) {
  int i = blockIdx.x * blockDim.x + threadIdx.x;
  if (i < n) start[i] += bsum[i >> 11];
}

__global__ __launch_bounds__(256) void k_build(const int* __restrict__ row,
                                               const int* __restrict__ col,
                                               unsigned* __restrict__ start,
                                               int* __restrict__ colS, int nE) {
  int i = blockIdx.x * blockDim.x + threadIdx.x;
  int stride = gridDim.x * blockDim.x;
  for (; i < nE; i += stride) {
    int r = row[i];
    unsigned p = atomicAdd(&start[r], 1u);
    colS[p] = col[i];
  }
}

// ---------------- shared compute kernels ------------------------------------
__global__ __launch_bounds__(256) void k_gemm_dual(
    const float* __restrict__ x, const float* __restrict__ W,
    const float* __restrict__ b, const float* __restrict__ Wr,
    const float* __restrict__ br, float* __restrict__ h,
    float* __restrict__ agg, int nNodes, int reluIn)
{
  __shared__ float4 xrow4[4][16];
  const int t = threadIdx.x, wave = t >> 6, lane = t & 63;
  const float4* W4  = (const float4*)W;
  const float4* Wr4 = (const float4*)Wr;
  float4 w4[16], wr4[16];
#pragma unroll
  for (int i = 0; i < 16; ++i) { w4[i] = W4[lane * 16 + i]; wr4[i] = Wr4[lane * 16 + i]; }
  const float bo = b[lane], bro = br[lane];
  float* xs = (float*)&xrow4[wave][0];
  const int gw = blockIdx.x * 4 + wave, nW = gridDim.x * 4;
  for (int n = gw; n < nNodes; n += nW) {
    float xv = x[(size_t)n * 64 + lane];
    if (reluIn) xv = fmaxf(xv, 0.f);
    xs[lane] = xv;
    float ha = bo, aa = bro;
#pragma unroll
    for (int k4 = 0; k4 < 16; ++k4) {
      float4 xk = xrow4[wave][k4];
      ha += xk.x * w4[k4].x + xk.y * w4[k4].y + xk.z * w4[k4].z + xk.w * w4[k4].w;
      aa += xk.x * wr4[k4].x + xk.y * wr4[k4].y + xk.z * wr4[k4].z + xk.w * wr4[k4].w;
    }
    h[(size_t)n * 64 + lane]   = ha;
    agg[(size_t)n * 64 + lane] = aa;
  }
}

// agg[n,:] += dis[n] * sum_{e in seg(n)} dis[colS[e]] * h[colS[e],:]
// one wave per node; 4 edge-groups x 16 lanes; float4 gathers, 2-deep unroll.
__global__ __launch_bounds__(256) void k_spmm(
    const float* __restrict__ h, float* __restrict__ agg,
    const int* __restrict__ colS, const unsigned* __restrict__ startEnd,
    const float* __restrict__ dis, int nNodes)
{
  const int t = threadIdx.x, wave = t >> 6, lane = t & 63;
  const int g = lane >> 4, sub = lane & 15;
  const int n = blockIdx.x * 4 + wave;
  if (n >= nNodes) return;
  const unsigned lo = n ? startEnd[n - 1] : 0u;
  const unsigned hi = startEnd[n];
  const float4* h4 = (const float4*)h;
  float ax = 0.f, ay = 0.f, az = 0.f, aw = 0.f;
  for (unsigned base = lo; base < hi; base += 64) {
    const int cnt = (int)min(64u, hi - base);
    int   myc = (lane < cnt) ? colS[base + lane] : 0;
    float myw = (lane < cnt) ? dis[myc] : 0.f;
    // 8 edges in flight per iteration (two independent gathers).
    // Shuffle indices stay <= 63; lanes >= cnt carry w=0 so no guards needed.
    for (int j = 0; j < cnt; j += 8) {
      int j0 = j + g, j1 = j + 4 + g;
      int   c0 = __shfl(myc, j0);
      float w0 = __shfl(myw, j0);
      int   c1 = __shfl(myc, j1);
      float w1 = __shfl(myw, j1);
      float4 v0 = h4[(size_t)c0 * 16 + sub];
      float4 v1 = h4[(size_t)c1 * 16 + sub];
      ax += w0 * v0.x; ay += w0 * v0.y; az += w0 * v0.z; aw += w0 * v0.w;
      ax += w1 * v1.x; ay += w1 * v1.y; az += w1 * v1.z; aw += w1 * v1.w;
    }
  }
  ax += __shfl_xor(ax, 16); ay += __shfl_xor(ay, 16);
  az += __shfl_xor(az, 16); aw += __shfl_xor(aw, 16);
  ax += __shfl_xor(ax, 32); ay += __shfl_xor(ay, 32);
  az += __shfl_xor(az, 32); aw += __shfl_xor(aw, 32);
  if (lane < 16) {
    const float dn = dis[n];
    float4* a4 = (float4*)(agg + (size_t)n * 64);
    float4 o = a4[sub];
    o.x += dn * ax; o.y += dn * ay; o.z += dn * az; o.w += dn * aw;
    a4[sub] = o;
  }
}

// out[n,:] = log_softmax( concat(relu(agg1[n]), relu(agg2[n])) @ Wl^T + bl )
// 64 nodes / block. lane = node, wave = output-group of 10 (uniform -> scalar
// Wl loads). x tile in LDS, stride 33 float4 (8 words/bank floor, no conflict).
__global__ __launch_bounds__(256) void k_final(
    const float* __restrict__ agg1, const float* __restrict__ agg2,
    const float* __restrict__ Wl, const float* __restrict__ bl,
    float* __restrict__ out, int nNodes)
{
  __shared__ float4 xs[64][33];
  __shared__ float redM[64][4];
  __shared__ float redS[64][4];
  const int t = threadIdx.x;
  const int lane = t & 63;
  const int og = __builtin_amdgcn_readfirstlane(t >> 6);   // 0..3, wave-uniform
  const int nodeBase = blockIdx.x * 64;

  // stage 64 rows of concat(relu(agg1),relu(agg2)): thread = (node, quarter)
  {
    const int sn = t >> 2, q = t & 3;
    int gn = nodeBase + sn;
    if (gn > nNodes - 1) gn = nNodes - 1;
    const float4* a1 = (const float4*)(agg1 + (size_t)gn * 64);
    const float4* a2 = (const float4*)(agg2 + (size_t)gn * 64);
#pragma unroll
    for (int j = 0; j < 4; ++j) {
      float4 v = a1[q * 4 + j];
      xs[sn][q * 4 + j] = make_float4(fmaxf(v.x, 0.f), fmaxf(v.y, 0.f),
                                      fmaxf(v.z, 0.f), fmaxf(v.w, 0.f));
      float4 u = a2[q * 4 + j];
      xs[sn][16 + q * 4 + j] = make_float4(fmaxf(u.x, 0.f), fmaxf(u.y, 0.f),
                                           fmaxf(u.z, 0.f), fmaxf(u.w, 0.f));
    }
  }
  __syncthreads();

  // 10 logits per thread; Wl rows are wave-uniform -> scalar loads.
  const float4* W4 = (const float4*)Wl;
  float acc[10];
#pragma unroll
  for (int j = 0; j < 10; ++j) acc[j] = bl[og * 10 + j];
  for (int k = 0; k < 32; ++k) {
    float4 x = xs[lane][k];
#pragma unroll
    for (int j = 0; j < 10; ++j) {
      float4 w = W4[(og * 10 + j) * 32 + k];
      acc[j] += w.x * x.x + w.y * x.y + w.z * x.z + w.w * x.w;
    }
  }

  // cross-wave log-softmax (4 waves hold 10 logits each for the same node)
  float m10 = acc[0];
#pragma unroll
  for (int j = 1; j < 10; ++j) m10 = fmaxf(m10, acc[j]);
  redM[lane][og] = m10;
  __syncthreads();
  float M = fmaxf(fmaxf(redM[lane][0], redM[lane][1]),
                  fmaxf(redM[lane][2], redM[lane][3]));
  float s10 = 0.f;
#pragma unroll
  for (int j = 0; j < 10; ++j) s10 += __expf(acc[j] - M);
  redS[lane][og] = s10;
  __syncthreads();
  const float S = redS[lane][0] + redS[lane][1] + redS[lane][2] + redS[lane][3];
  const float lse = M + __logf(S);

  const int n = nodeBase + lane;
  if (n < nNodes) {
    float2* o2 = (float2*)(out + (size_t)n * 40 + og * 10);
#pragma unroll
    for (int q = 0; q < 5; ++q)
      o2[q] = make_float2(acc[2 * q] - lse, acc[2 * q + 1] - lse);
  }
}

extern "C" void kernel_launch(void* const* d_in, const int* in_sizes, int n_in,
                              void* d_out, int out_size, void* d_ws, size_t ws_size,
                              hipStream_t stream) {
  const float* x0  = (const float*)d_in[0];
  const int*   ei  = (const int*)d_in[1];
  const float* W1  = (const float*)d_in[2];
  const float* b1  = (const float*)d_in[3];
  const float* Wr1 = (const float*)d_in[4];
  const float* br1 = (const float*)d_in[5];
  const float* W2  = (const float*)d_in[6];
  const float* b2  = (const float*)d_in[7];
  const float* Wr2 = (const float*)d_in[8];
  const float* br2 = (const float*)d_in[9];
  const float* Wl  = (const float*)d_in[10];
  const float* bl  = (const float*)d_in[11];
  float* out = (float*)d_out;

  const int N = in_sizes[0] / 64;
  const int E = in_sizes[1] / 2;
  const int* row = ei;
  const int* col = ei + E;

  const int NB = (N + BROWS - 1) / BROWS;
  const int capA = 12288;
  const int avg = E / (NB > 0 ? NB : 1);
  const bool binOK = (N <= 131072) && (NB <= 256) &&
                     (avg + 12 * (int)sqrtf((float)avg + 1.f) + 256 <= capA);

  const size_t needBin = (size_t)4 * (512 + (size_t)NB * capA + (size_t)E + (size_t)2 * N + (size_t)192 * N);
  const size_t needCSR = (size_t)4 * ((size_t)3 * N + 64 + (size_t)E + (size_t)192 * N);

  if (binOK && ws_size >= needBin) {
    unsigned* bCnt  = (unsigned*)d_ws;
    unsigned* bBase = bCnt + 256;
    unsigned* pairs = bBase + 256;
    int*      colS  = (int*)(pairs + (size_t)NB * capA);
    unsigned* start = (unsigned*)(colS + E);
    float*    dis   = (float*)(start + N);
    float*    h     = dis + N;
    float*    agg1  = h + (size_t)64 * N;
    float*    agg2  = agg1 + (size_t)64 * N;

    hipMemsetAsync(bCnt, 0, 256 * 4, stream);
    k_binA<<<(E + BIN_CHUNK - 1) / BIN_CHUNK, 256, 0, stream>>>(row, col, bCnt, pairs, E, NB, capA);
    k_bscan<<<1, 256, 0, stream>>>(bCnt, bBase, NB, capA);
    k_binB<<<NB, 256, 0, stream>>>(pairs, bCnt, bBase, colS, start, dis, N, capA);

    k_gemm_dual<<<2048, 256, 0, stream>>>(x0, W1, b1, Wr1, br1, h, agg1, N, 0);
    k_spmm<<<(N + 3) / 4, 256, 0, stream>>>(h, agg1, colS, start, dis, N);

    k_gemm_dual<<<2048, 256, 0, stream>>>(agg1, W2, b2, Wr2, br2, h, agg2, N, 1);
    k_spmm<<<(N + 3) / 4, 256, 0, stream>>>(h, agg2, colS, start, dis, N);

    k_final<<<(N + 63) / 64, 256, 0, stream>>>(agg1, agg2, Wl, bl, out, N);
  } else if (ws_size >= needCSR) {
    unsigned* deg   = (unsigned*)d_ws;
    unsigned* start = deg + N;
    float*    dis   = (float*)(start + N);
    unsigned* bsum  = (unsigned*)(dis + N);
    int*      colS  = (int*)(bsum + 64);
    float*    h     = (float*)(colS + E);
    float*    agg1  = h + (size_t)64 * N;
    float*    agg2  = agg1 + (size_t)64 * N;

    const int nB = (N + 2047) / 2048;

    hipMemsetAsync(deg, 0, (size_t)N * 4, stream);
    k_deg<<<1024, 256, 0, stream>>>(row, deg, E);
    k_dis<<<(N + 255) / 256, 256, 0, stream>>>(deg, dis, N);
    k_scan1<<<nB, 256, 0, stream>>>(deg, start, bsum, N);
    k_scan2<<<1, 64, 0, stream>>>(bsum, nB);
    k_scan3<<<(N + 255) / 256, 256, 0, stream>>>(start, bsum, N);
    k_build<<<1024, 256, 0, stream>>>(row, col, start, colS, E);

    k_gemm_dual<<<2048, 256, 0, stream>>>(x0, W1, b1, Wr1, br1, h, agg1, N, 0);
    k_spmm<<<(N + 3) / 4, 256, 0, stream>>>(h, agg1, colS, start, dis, N);

    k_gemm_dual<<<2048, 256, 0, stream>>>(agg1, W2, b2, Wr2, br2, h, agg2, N, 1);
    k_spmm<<<(N + 3) / 4, 256, 0, stream>>>(h, agg2, colS, start, dis, N);

    k_final<<<(N + 63) / 64, 256, 0, stream>>>(agg1, agg2, Wl, bl, out, N);
  }
}